// Round 9
// baseline (232.528 us; speedup 1.0000x reference)
//
#include <hip/hip_runtime.h>
#include <math.h>

typedef unsigned short u16;
typedef unsigned int u32;
typedef __fp16 fp16x2 __attribute__((ext_vector_type(2)));
typedef _Float16 half8 __attribute__((ext_vector_type(8)));
typedef float f32x4 __attribute__((ext_vector_type(4)));

#define NH   12
#define SEQ  2048
#define CDIM 768

__device__ __forceinline__ u16 f2h(float f) {
  _Float16 h = (_Float16)f;
  return __builtin_bit_cast(u16, h);
}
__device__ __forceinline__ u32 pk2(float a, float b) {
  fp16x2 h = __builtin_amdgcn_cvt_pkrtz(a, b);    // v_cvt_pk_rtz_f16_f32
  return __builtin_bit_cast(u32, h);
}
// async global->LDS DMA, 16B per lane; LDS dest = wave-uniform base + lane*16
__device__ __forceinline__ void dma16(const u16* g, u16* l) {
  __builtin_amdgcn_global_load_lds(
      (const __attribute__((address_space(1))) u32*)g,
      (__attribute__((address_space(3))) u32*)l, 16, 0, 0);
}

// ---------------- single fused fp32 -> f16 convert (x, y, all weights) -----
// Each block converts 1024 contiguous elements of exactly one tensor.
// Ranges (in blocks): x [0,6144), y [6144,12288), Wq-scaled [12288,12864),
// Wkv [12864,14016), Wproj [14016,14592). Offsets in ELEMENTS throughout.
__global__ __launch_bounds__(256) void cvt_all(
    const float* __restrict__ x, const float* __restrict__ y,
    const float* __restrict__ Wq, const float* __restrict__ Wkv,
    const float* __restrict__ Wp, const float* __restrict__ taup,
    u16* __restrict__ xh, u16* __restrict__ yh,
    u16* __restrict__ wqh, u16* __restrict__ wkh, u16* __restrict__ wph)
{
  const int bx = blockIdx.x;
  const long idx = (long)bx * 1024 + (long)threadIdx.x * 4;  // global elem idx
  const float* in; u16* out; long j; float s = 1.f;
  if (bx < 6144)       { in = x;   out = xh;  j = idx; }
  else if (bx < 12288) { in = y;   out = yh;  j = idx - 6144l * 1024; }
  else if (bx < 12864) {
    float t = *taup;
    float sp = (t > 20.f) ? t : log1pf(expf(t));
    s = (0.125f / (sp + 1e-6f)) * 1.44269504088896340736f;  // qkscale * log2(e)
    in = Wq; out = wqh; j = idx - 12288l * 1024;
  }
  else if (bx < 14016) { in = Wkv; out = wkh; j = idx - 12864l * 1024; }
  else                 { in = Wp;  out = wph; j = idx - 14016l * 1024; }
  float4 f = *(const float4*)(in + j);
  *(uint2*)(out + j) = make_uint2(pk2(f.x * s, f.y * s), pk2(f.z * s, f.w * s));
}

// ---------------- NT GEMM: C[M,N] = A[M,K] @ B[N,K]^T, f16 MFMA, fp32 acc ---
// R4-proven structure: tile 128(M) x BN(N), BK=64, K=768 (12 iters), 4 waves
// as 2x2 quadrants, all-DMA staging (global_load_lds f16), 2-phase prefetch
// (issue t+1 before compute t), one __syncthreads per iter. Chunk-XOR swizzle.
// MODE 0: FUSED QKV. by<6: A=xh,B=Wq -> q [B,H,N,D] (scale pre-folded);
//         by>=6: A=yh,B=Wkv -> cols[0,768) k; [768,1536) v^T [B,H,D,N]
//         (v^T stored as 8B uint2: 4 consecutive n per lane)
// MODE 2: A=ao,B=Wproj -> fp32 out[M,768] = acc + bias[n]
template<int MODE, int BN, int WPB>
__global__ __launch_bounds__(256, WPB) void gemm_k(
    const u16* __restrict__ A0, const u16* __restrict__ A1,
    const u16* __restrict__ B0, const u16* __restrict__ B1,
    u16* __restrict__ oq, u16* __restrict__ ok, u16* __restrict__ ovt,
    float* __restrict__ outf, const float* __restrict__ bias)
{
  constexpr int NT = BN / 32;                     // n-tiles per wave
  __shared__ __align__(16) u16 As[2][128 * 64];   // [buf][m][k] swizzled, 32 KB
  __shared__ __align__(16) u16 Bs[2][BN * 64];    // [buf][n][k] swizzled
  const int tid = threadIdx.x;
  const int wave = tid >> 6, lane = tid & 63;
  const int quad = lane >> 4, l16 = lane & 15;
  const int wr = wave >> 1, wc = wave & 1;        // wave quadrant (64m x BN/2)
  const int row0 = blockIdx.x * 128;
  const int by = blockIdx.y;

  const u16* A; const u16* Bm; int cb;
  if (MODE == 0) {
    if (by < 6) { A = A0; Bm = B0; cb = by; }
    else        { A = A1; Bm = B1; cb = by - 6; }
  } else {
    A = A0; Bm = B0; cb = by;
  }
  const int col0 = cb * BN;

  const int sub = lane >> 3;                   // row within an 8-row DMA slab
  const int csw = ((lane & 7) ^ sub) * 8;      // swizzled source chunk (elems)

  f32x4 acc[4][NT] = {};

  auto stage = [&](int k0, int bsel) {
    #pragma unroll
    for (int i = 0; i < 4; i++) {
      int ii = wave * 4 + i;                   // A slabs 0..15 (8 rows each)
      dma16(A + (size_t)(row0 + ii * 8 + sub) * 768 + k0 + csw, &As[bsel][ii * 512]);
    }
    #pragma unroll
    for (int i = 0; i < BN / 32; i++) {
      int ii = wave * (BN / 32) + i;           // B slabs
      dma16(Bm + (size_t)(col0 + ii * 8 + sub) * 768 + k0 + csw, &Bs[bsel][ii * 512]);
    }
  };

  stage(0, 0);
  __syncthreads();                             // drain tile-0 DMA

  #pragma unroll 1
  for (int t = 0; t < 12; t++) {
    const int cur = t & 1;
    if (t + 1 < 12) stage((t + 1) << 6, cur ^ 1);   // prefetch next tile
    const u16* Asp = As[cur];
    const u16* Bsp = Bs[cur];
    #pragma unroll
    for (int ks = 0; ks < 2; ks++) {
      half8 af[4], bfr[NT];
      #pragma unroll
      for (int mt = 0; mt < 4; mt++)
        af[mt] = *(const half8*)&Asp[(wr * 64 + mt * 16 + l16) * 64 + (((ks * 4 + quad) ^ (l16 & 7)) * 8)];
      #pragma unroll
      for (int nt = 0; nt < NT; nt++)
        bfr[nt] = *(const half8*)&Bsp[(wc * (BN / 2) + nt * 16 + l16) * 64 + (((ks * 4 + quad) ^ (l16 & 7)) * 8)];
      #pragma unroll
      for (int mt = 0; mt < 4; mt++)
        #pragma unroll
        for (int nt = 0; nt < NT; nt++)
          acc[mt][nt] = __builtin_amdgcn_mfma_f32_16x16x32_f16(af[mt], bfr[nt], acc[mt][nt], 0, 0, 0);
    }
    __syncthreads();   // readers done with buf[cur]; prefetch DMA drained
  }

  // epilogue: C layout col=lane&15, row=quad*4+reg
  #pragma unroll
  for (int mt = 0; mt < 4; mt++)
  #pragma unroll
  for (int nt = 0; nt < NT; nt++) {
    int gm0 = row0 + wr * 64 + mt * 16 + quad * 4;
    int gn = col0 + wc * (BN / 2) + nt * 16 + l16;
    f32x4 v = acc[mt][nt];
    if (MODE == 0) {
      int b = gm0 >> 11, n0 = gm0 & 2047;
      if (by < 6) {
        int h = gn >> 6, d = gn & 63;
        size_t base = (((size_t)(b * NH + h)) * SEQ + n0) * 64 + d;
        #pragma unroll
        for (int r = 0; r < 4; r++) oq[base + (size_t)r * 64] = f2h(v[r]);
      } else if (gn < CDIM) {
        int h = gn >> 6, d = gn & 63;
        size_t base = (((size_t)(b * NH + h)) * SEQ + n0) * 64 + d;
        #pragma unroll
        for (int r = 0; r < 4; r++) ok[base + (size_t)r * 64] = f2h(v[r]);
      } else {
        int c = gn - CDIM;
        int h = c >> 6, d = c & 63;
        *(uint2*)&ovt[(((size_t)(b * NH + h)) * 64 + d) * SEQ + n0] =
            make_uint2(pk2(v[0], v[1]), pk2(v[2], v[3]));   // V^T: 4 consecutive n
      }
    } else {
      float bv = bias[gn];
      #pragma unroll
      for (int r = 0; r < 4; r++)
        outf[(size_t)(gm0 + r) * CDIM + gn] = v[r] + bv;
    }
  }
}

// ---------------- flash attention (transposed-S, f16, no-max softmax) ------
// NEW: 8 waves x 16 q-rows (512 threads) instead of 4 x 32. Same QBLK=128,
// same per-block staging (16 DMAs -> 2/wave), per-wave MFMA halves (18/tile)
// -> staging:MFMA ratio preserved (the R3 QBLK=64 trap halved it instead).
// LDS: Ks 16K + Vs 16K + Ps 8x2K = 48 KB -> 3 blocks/CU = 24 waves/CU =
// 6 waves/SIMD (was 3). Rationale: R6 proved barrier drain/prefetch cover are
// not the cost; both pipes ~35% busy with nothing saturated = too few
// independent streams per SIMD to cover the QK->exp2->relayout->PV chain.
// Doubling streams should raise MfmaUtil toward 55-70%.
// __launch_bounds__(512,6) caps VGPR at 85 to hold 6 waves/SIMD (mt=1 body
// needs ~75). grid 768, chunked XCD swizzle (96 blocks = 6 heads/XCD).
__global__ __launch_bounds__(512, 6) void attn_kernel(
    const u16* __restrict__ Q, const u16* __restrict__ Kb,
    const u16* __restrict__ Vtg, u16* __restrict__ Ob)
{
  __shared__ __align__(16) u16 Ks[2][64 * 64];    // [buf][kk][d] swizzled, 2x8 KB
  __shared__ __align__(16) u16 Vs[2][64 * 64];    // [buf][d][kk] swizzled, 2x8 KB
  __shared__ __align__(16) u16 Ps[8 * 16 * 64];   // per-wave 16x64 swizzled, 16 KB

  // bijective chunked XCD swizzle: 768 blocks = 8 XCDs x 96
  const int bid = (blockIdx.x & 7) * 96 + (blockIdx.x >> 3);
  const int qt = bid & 15;
  const int bh = bid >> 4;
  const int b = bh / NH, h = bh % NH;
  const u16* Qp = Q   + (size_t)bh * SEQ * 64;
  const u16* Kp = Kb  + (size_t)bh * SEQ * 64;
  const u16* Vp = Vtg + (size_t)bh * 64 * SEQ;

  const int tid = threadIdx.x;
  const int wave = tid >> 6, lane = tid & 63;     // wave 0..7
  const int quad = lane >> 4, l16 = lane & 15;
  const int sub = lane >> 3;
  const int csw = ((lane & 7) ^ sub) * 8;
  u16* Pw = Ps + wave * 1024;                     // private 16x64 relayout buf

  half8 vone;
  #pragma unroll
  for (int j = 0; j < 8; j++) vone[j] = (_Float16)1.0f;

  // Q fragments (B-operand): Q[m=l16][d=ks*32+quad*8+j], scale pre-folded
  half8 qf[2];
  #pragma unroll
  for (int ks = 0; ks < 2; ks++)
    qf[ks] = *(const half8*)(Qp + (size_t)(qt * 128 + wave * 16 + l16) * 64 + ks * 32 + quad * 8);

  f32x4 oacc[4] = {};
  f32x4 lacc = {};                             // row-sums via MFMA w/ ones

  auto stage = [&](int kt, int bsel) {
    int ii = wave;                             // one K slab + one V slab/wave
    dma16(Kp + (size_t)(kt * 64 + ii * 8 + sub) * 64 + csw, &Ks[bsel][ii * 512]);
    dma16(Vp + (size_t)(ii * 8 + sub) * SEQ + kt * 64 + csw, &Vs[bsel][ii * 512]);
  };

  stage(0, 0);
  __syncthreads();                             // drain tile-0 DMA

  #pragma unroll 1
  for (int kt = 0; kt < SEQ / 64; kt++) {
    const int cur = kt & 1;
    if (kt + 1 < SEQ / 64) stage(kt + 1, cur ^ 1);   // prefetch next K/V tile
    const u16* Ksp = Ks[cur];
    const u16* Vsp = Vs[cur];

    // St = K Q^T : sacc[ntk] holds St[kk=ntk*16+quad*4+r][m=l16]
    f32x4 sacc[4] = {};
    __builtin_amdgcn_s_setprio(1);
    #pragma unroll
    for (int ks = 0; ks < 2; ks++) {
      #pragma unroll
      for (int ntk = 0; ntk < 4; ntk++) {
        half8 kf = *(const half8*)&Ksp[(ntk * 16 + l16) * 64 + (((ks * 4 + quad) ^ (l16 & 7)) * 8)];
        sacc[ntk] = __builtin_amdgcn_mfma_f32_16x16x32_f16(kf, qf[ks], sacc[ntk], 0, 0, 0);
      }
    }
    __builtin_amdgcn_s_setprio(0);

    // softmax (fixed shift): p = exp2(s); P -> swizzled Ps (C->A layout)
    #pragma unroll
    for (int ntk = 0; ntk < 4; ntk++) {
      float p0 = __builtin_amdgcn_exp2f(sacc[ntk][0]);
      float p1 = __builtin_amdgcn_exp2f(sacc[ntk][1]);
      float p2 = __builtin_amdgcn_exp2f(sacc[ntk][2]);
      float p3 = __builtin_amdgcn_exp2f(sacc[ntk][3]);
      *(uint2*)&Pw[l16 * 64 + (((ntk * 2 + (quad >> 1)) ^ (l16 & 7)) * 8) + (quad & 1) * 4] =
          make_uint2(pk2(p0, p1), pk2(p2, p3));
    }
    half8 pf[2];
    pf[0] = *(const half8*)&Pw[l16 * 64 + ((quad ^ (l16 & 7)) * 8)];
    pf[1] = *(const half8*)&Pw[l16 * 64 + (((4 + quad) ^ (l16 & 7)) * 8)];

    // O += P V; l += P 1 on the matrix pipe
    __builtin_amdgcn_s_setprio(1);
    #pragma unroll
    for (int ks = 0; ks < 2; ks++) {
      #pragma unroll
      for (int dt = 0; dt < 4; dt++) {
        half8 vf = *(const half8*)&Vsp[(dt * 16 + l16) * 64 + (((ks * 4 + quad) ^ (l16 & 7)) * 8)];
        oacc[dt] = __builtin_amdgcn_mfma_f32_16x16x32_f16(pf[ks], vf, oacc[dt], 0, 0, 0);
      }
      lacc = __builtin_amdgcn_mfma_f32_16x16x32_f16(pf[ks], vone, lacc, 0, 0, 0);
    }
    __builtin_amdgcn_s_setprio(0);

    __syncthreads();   // readers done with buf[cur]; prefetch DMA drained
  }

  // epilogue: O / l -> ao[b][n][h*64+d] (f16); lacc row layout == oacc rows
  #pragma unroll
  for (int r = 0; r < 4; r++) {
    float inv = 1.0f / lacc[r];
    int n = qt * 128 + wave * 16 + quad * 4 + r;
    size_t base = ((size_t)b * SEQ + n) * CDIM + h * 64;
    #pragma unroll
    for (int dt = 0; dt < 4; dt++)
      Ob[base + dt * 16 + l16] = f2h(oacc[dt][r] * inv);
  }
}

// ---------------- launch ----------------
extern "C" void kernel_launch(void* const* d_in, const int* in_sizes, int n_in,
                              void* d_out, int out_size, void* d_ws, size_t ws_size,
                              hipStream_t stream)
{
  const float* x     = (const float*)d_in[0];
  const float* y     = (const float*)d_in[1];
  const float* Wq    = (const float*)d_in[2];
  const float* Wkv   = (const float*)d_in[3];
  const float* taup  = (const float*)d_in[4];
  const float* Wproj = (const float*)d_in[5];
  const float* bproj = (const float*)d_in[6];
  float* out = (float*)d_out;

  char* ws = (char*)d_ws;
  size_t off = 0;
  auto alloc = [&](size_t bytes) { char* p = ws + off; off += bytes; return p; };
  u16* xh  = (u16*)alloc(8192ull * 768 * 2);
  u16* yh  = (u16*)alloc(8192ull * 768 * 2);
  u16* wqh = (u16*)alloc(768ull * 768 * 2);
  u16* wkh = (u16*)alloc(1536ull * 768 * 2);
  u16* wph = (u16*)alloc(768ull * 768 * 2);
  u16* qb  = (u16*)alloc(8192ull * 768 * 2);   // [B,H,N,D] f16, scale folded
  u16* kb  = (u16*)alloc(8192ull * 768 * 2);   // [B,H,N,D]
  u16* vtb = (u16*)alloc(8192ull * 768 * 2);   // [B,H,D,N]
  u16* ao  = (u16*)alloc(8192ull * 768 * 2);   // [B,N,C]

  // one fused convert kernel: x, y, Wq(scaled), Wkv, Wproj
  cvt_all<<<14592, 256, 0, stream>>>(x, y, Wq, Wkv, Wproj, taup,
                                     xh, yh, wqh, wkh, wph);

  // fused QKV GEMM: by<6 -> Q (N=768), by in [6,18) -> KV (N=1536), BN=128
  gemm_k<0, 128, 2><<<dim3(64, 18), 256, 0, stream>>>(xh, yh, wqh, wkh, qb, kb, vtb, nullptr, nullptr);
  attn_kernel<<<dim3(768), 512, 0, stream>>>(qb, kb, vtb, ao);
  gemm_k<2, 64, 3><<<dim3(64, 12), 256, 0, stream>>>(ao, nullptr, wph, nullptr, nullptr, nullptr, nullptr, out, bproj);
}

// Round 10
// 231.764 us; speedup vs baseline: 1.0033x; 1.0033x over previous
//
#include <hip/hip_runtime.h>
#include <math.h>

typedef unsigned short u16;
typedef unsigned int u32;
typedef __fp16 fp16x2 __attribute__((ext_vector_type(2)));
typedef _Float16 half8 __attribute__((ext_vector_type(8)));
typedef float f32x4 __attribute__((ext_vector_type(4)));

#define NH   12
#define SEQ  2048
#define CDIM 768

__device__ __forceinline__ u16 f2h(float f) {
  _Float16 h = (_Float16)f;
  return __builtin_bit_cast(u16, h);
}
__device__ __forceinline__ u32 pk2(float a, float b) {
  fp16x2 h = __builtin_amdgcn_cvt_pkrtz(a, b);    // v_cvt_pk_rtz_f16_f32
  return __builtin_bit_cast(u32, h);
}
// async global->LDS DMA, 16B per lane; LDS dest = wave-uniform base + lane*16
__device__ __forceinline__ void dma16(const u16* g, u16* l) {
  __builtin_amdgcn_global_load_lds(
      (const __attribute__((address_space(1))) u32*)g,
      (__attribute__((address_space(3))) u32*)l, 16, 0, 0);
}

// ---------------- single fused fp32 -> f16 convert (x, y, all weights) -----
// Each block converts 1024 contiguous elements of exactly one tensor.
// Ranges (in blocks): x [0,6144), y [6144,12288), Wq-scaled [12288,12864),
// Wkv [12864,14016), Wproj [14016,14592). Offsets in ELEMENTS throughout.
__global__ __launch_bounds__(256) void cvt_all(
    const float* __restrict__ x, const float* __restrict__ y,
    const float* __restrict__ Wq, const float* __restrict__ Wkv,
    const float* __restrict__ Wp, const float* __restrict__ taup,
    u16* __restrict__ xh, u16* __restrict__ yh,
    u16* __restrict__ wqh, u16* __restrict__ wkh, u16* __restrict__ wph)
{
  const int bx = blockIdx.x;
  const long idx = (long)bx * 1024 + (long)threadIdx.x * 4;  // global elem idx
  const float* in; u16* out; long j; float s = 1.f;
  if (bx < 6144)       { in = x;   out = xh;  j = idx; }
  else if (bx < 12288) { in = y;   out = yh;  j = idx - 6144l * 1024; }
  else if (bx < 12864) {
    float t = *taup;
    float sp = (t > 20.f) ? t : log1pf(expf(t));
    s = (0.125f / (sp + 1e-6f)) * 1.44269504088896340736f;  // qkscale * log2(e)
    in = Wq; out = wqh; j = idx - 12288l * 1024;
  }
  else if (bx < 14016) { in = Wkv; out = wkh; j = idx - 12864l * 1024; }
  else                 { in = Wp;  out = wph; j = idx - 14016l * 1024; }
  float4 f = *(const float4*)(in + j);
  *(uint2*)(out + j) = make_uint2(pk2(f.x * s, f.y * s), pk2(f.z * s, f.w * s));
}

// ---------------- NT GEMM: C[M,N] = A[M,K] @ B[N,K]^T, f16 MFMA, fp32 acc ---
// R4-proven structure: tile 128(M) x BN(N), BK=64, K=768 (12 iters), 4 waves
// as 2x2 quadrants, all-DMA staging (global_load_lds f16), 2-phase prefetch
// (issue t+1 before compute t), one __syncthreads per iter. Chunk-XOR swizzle.
// MODE 0: FUSED QKV. by<6: A=xh,B=Wq -> q [B,H,N,D] (scale pre-folded);
//         by>=6: A=yh,B=Wkv -> cols[0,768) k; [768,1536) v^T [B,H,D,N]
//         (v^T stored as 8B uint2: 4 consecutive n per lane)
// MODE 2: A=ao,B=Wproj -> fp32 out[M,768] = acc + bias[n]
template<int MODE, int BN, int WPB>
__global__ __launch_bounds__(256, WPB) void gemm_k(
    const u16* __restrict__ A0, const u16* __restrict__ A1,
    const u16* __restrict__ B0, const u16* __restrict__ B1,
    u16* __restrict__ oq, u16* __restrict__ ok, u16* __restrict__ ovt,
    float* __restrict__ outf, const float* __restrict__ bias)
{
  constexpr int NT = BN / 32;                     // n-tiles per wave
  __shared__ __align__(16) u16 As[2][128 * 64];   // [buf][m][k] swizzled, 32 KB
  __shared__ __align__(16) u16 Bs[2][BN * 64];    // [buf][n][k] swizzled
  const int tid = threadIdx.x;
  const int wave = tid >> 6, lane = tid & 63;
  const int quad = lane >> 4, l16 = lane & 15;
  const int wr = wave >> 1, wc = wave & 1;        // wave quadrant (64m x BN/2)
  const int row0 = blockIdx.x * 128;
  const int by = blockIdx.y;

  const u16* A; const u16* Bm; int cb;
  if (MODE == 0) {
    if (by < 6) { A = A0; Bm = B0; cb = by; }
    else        { A = A1; Bm = B1; cb = by - 6; }
  } else {
    A = A0; Bm = B0; cb = by;
  }
  const int col0 = cb * BN;

  const int sub = lane >> 3;                   // row within an 8-row DMA slab
  const int csw = ((lane & 7) ^ sub) * 8;      // swizzled source chunk (elems)

  f32x4 acc[4][NT] = {};

  auto stage = [&](int k0, int bsel) {
    #pragma unroll
    for (int i = 0; i < 4; i++) {
      int ii = wave * 4 + i;                   // A slabs 0..15 (8 rows each)
      dma16(A + (size_t)(row0 + ii * 8 + sub) * 768 + k0 + csw, &As[bsel][ii * 512]);
    }
    #pragma unroll
    for (int i = 0; i < BN / 32; i++) {
      int ii = wave * (BN / 32) + i;           // B slabs
      dma16(Bm + (size_t)(col0 + ii * 8 + sub) * 768 + k0 + csw, &Bs[bsel][ii * 512]);
    }
  };

  stage(0, 0);
  __syncthreads();                             // drain tile-0 DMA

  #pragma unroll 1
  for (int t = 0; t < 12; t++) {
    const int cur = t & 1;
    if (t + 1 < 12) stage((t + 1) << 6, cur ^ 1);   // prefetch next tile
    const u16* Asp = As[cur];
    const u16* Bsp = Bs[cur];
    #pragma unroll
    for (int ks = 0; ks < 2; ks++) {
      half8 af[4], bfr[NT];
      #pragma unroll
      for (int mt = 0; mt < 4; mt++)
        af[mt] = *(const half8*)&Asp[(wr * 64 + mt * 16 + l16) * 64 + (((ks * 4 + quad) ^ (l16 & 7)) * 8)];
      #pragma unroll
      for (int nt = 0; nt < NT; nt++)
        bfr[nt] = *(const half8*)&Bsp[(wc * (BN / 2) + nt * 16 + l16) * 64 + (((ks * 4 + quad) ^ (l16 & 7)) * 8)];
      #pragma unroll
      for (int mt = 0; mt < 4; mt++)
        #pragma unroll
        for (int nt = 0; nt < NT; nt++)
          acc[mt][nt] = __builtin_amdgcn_mfma_f32_16x16x32_f16(af[mt], bfr[nt], acc[mt][nt], 0, 0, 0);
    }
    __syncthreads();   // readers done with buf[cur]; prefetch DMA drained
  }

  // epilogue: C layout col=lane&15, row=quad*4+reg
  #pragma unroll
  for (int mt = 0; mt < 4; mt++)
  #pragma unroll
  for (int nt = 0; nt < NT; nt++) {
    int gm0 = row0 + wr * 64 + mt * 16 + quad * 4;
    int gn = col0 + wc * (BN / 2) + nt * 16 + l16;
    f32x4 v = acc[mt][nt];
    if (MODE == 0) {
      int b = gm0 >> 11, n0 = gm0 & 2047;
      if (by < 6) {
        int h = gn >> 6, d = gn & 63;
        size_t base = (((size_t)(b * NH + h)) * SEQ + n0) * 64 + d;
        #pragma unroll
        for (int r = 0; r < 4; r++) oq[base + (size_t)r * 64] = f2h(v[r]);
      } else if (gn < CDIM) {
        int h = gn >> 6, d = gn & 63;
        size_t base = (((size_t)(b * NH + h)) * SEQ + n0) * 64 + d;
        #pragma unroll
        for (int r = 0; r < 4; r++) ok[base + (size_t)r * 64] = f2h(v[r]);
      } else {
        int c = gn - CDIM;
        int h = c >> 6, d = c & 63;
        *(uint2*)&ovt[(((size_t)(b * NH + h)) * 64 + d) * SEQ + n0] =
            make_uint2(pk2(v[0], v[1]), pk2(v[2], v[3]));   // V^T: 4 consecutive n
      }
    } else {
      float bv = bias[gn];
      #pragma unroll
      for (int r = 0; r < 4; r++)
        outf[(size_t)(gm0 + r) * CDIM + gn] = v[r] + bv;
    }
  }
}

// ---------------- flash attention (transposed-S, f16, kk-split pairs) ------
// R9 diagnosis: 8x16-row waves hit the 85 B/cyc ds_read_b128 ceiling (each
// kf/vf read fed ONE MFMA). NEW: 8 waves, mt=2 (32 q-rows) but each wave
// owns HALF the kv tile (even waves kk 0-31, odd kk 32-63): kf 4 reads -> 8
// QK MFMA, vf 4 -> 8 PV (2x reuse, R4's intensity) at 8 waves/block. Pair
// (2w,2w+1) covers the same 32 q-rows; O/l partials merged once at epilogue
// through the then-dead K/V LDS region. Ps rows padded to 40 u16 (80 B,
// 16B-aligned): max 2-way bank aliasing (free) on P write+read, no XOR.
// LDS 52 KB; launch_bounds(512,4) (~96 VGPR) -> 16 waves/CU = 4/SIMD.
// grid 768, chunked XCD swizzle (96 blocks = 6 heads/XCD -> 3 MB K/V in L2).
__global__ __launch_bounds__(512, 4) void attn_kernel(
    const u16* __restrict__ Q, const u16* __restrict__ Kb,
    const u16* __restrict__ Vtg, u16* __restrict__ Ob)
{
  // carve: Ks 2x4096 | Vs 2x4096 | P 8x1280  (u16 units, 52 KB total)
  __shared__ __align__(16) u16 lds[26624];

  // bijective chunked XCD swizzle: 768 blocks = 8 XCDs x 96
  const int bid = (blockIdx.x & 7) * 96 + (blockIdx.x >> 3);
  const int qt = bid & 15;
  const int bh = bid >> 4;
  const int b = bh / NH, h = bh % NH;
  const u16* Qp = Q   + (size_t)bh * SEQ * 64;
  const u16* Kp = Kb  + (size_t)bh * SEQ * 64;
  const u16* Vp = Vtg + (size_t)bh * 64 * SEQ;

  const int tid = threadIdx.x;
  const int wave = tid >> 6, lane = tid & 63;     // wave 0..7
  const int quad = lane >> 4, l16 = lane & 15;
  const int sub = lane >> 3;
  const int csw = ((lane & 7) ^ sub) * 8;
  const int pair = wave >> 1;                     // 0..3: q-row block
  const int kh   = wave & 1;                      // kk half owner
  const int koff = kh * 32, koff8 = kh * 4;
  u16* Pw = &lds[16384] + wave * 1280;            // 2 x (16 rows x 40) relayout

  half8 vone;
  #pragma unroll
  for (int j = 0; j < 8; j++) vone[j] = (_Float16)1.0f;

  // Q fragments (B-operand): Q[q = pair*32+mt*16+l16][d = ks*32+quad*8+j]
  half8 qf[2][2];
  #pragma unroll
  for (int mt = 0; mt < 2; mt++)
    #pragma unroll
    for (int ks = 0; ks < 2; ks++)
      qf[mt][ks] = *(const half8*)(Qp + (size_t)(qt * 128 + pair * 32 + mt * 16 + l16) * 64 + ks * 32 + quad * 8);

  f32x4 oacc[2][4] = {};                       // partial over own kk half
  f32x4 lacc[2] = {};                          // partial row-sums (MFMA/ones)

  auto stage = [&](int kt, int bsel) {
    dma16(Kp + (size_t)(kt * 64 + wave * 8 + sub) * 64 + csw, &lds[bsel * 4096 + wave * 512]);
    dma16(Vp + (size_t)(wave * 8 + sub) * SEQ + kt * 64 + csw, &lds[8192 + bsel * 4096 + wave * 512]);
  };

  stage(0, 0);
  __syncthreads();                             // drain tile-0 DMA

  #pragma unroll 1
  for (int kt = 0; kt < SEQ / 64; kt++) {
    const int cur = kt & 1;
    if (kt + 1 < SEQ / 64) stage(kt + 1, cur ^ 1);   // prefetch next K/V tile
    const u16* Ksp = &lds[cur * 4096];
    const u16* Vsp = &lds[8192 + cur * 4096];

    // St = K Q^T over own kk half: sacc[mt][ntk] holds
    // St[kk = koff+ntk*16+quad*4+r][q = pair*32+mt*16+l16]
    f32x4 sacc[2][2] = {};
    __builtin_amdgcn_s_setprio(1);
    #pragma unroll
    for (int ks = 0; ks < 2; ks++) {
      #pragma unroll
      for (int ntk = 0; ntk < 2; ntk++) {
        half8 kf = *(const half8*)&Ksp[(koff + ntk * 16 + l16) * 64 + (((ks * 4 + quad) ^ (l16 & 7)) * 8)];
        #pragma unroll
        for (int mt = 0; mt < 2; mt++)
          sacc[mt][ntk] = __builtin_amdgcn_mfma_f32_16x16x32_f16(kf, qf[mt][ks], sacc[mt][ntk], 0, 0, 0);
      }
    }
    __builtin_amdgcn_s_setprio(0);

    // softmax (fixed shift): p = exp2(s); relayout via padded Ps (stride 40)
    half8 pf[2];
    #pragma unroll
    for (int mt = 0; mt < 2; mt++) {
      u16* Pmt = Pw + mt * 640;
      #pragma unroll
      for (int ntk = 0; ntk < 2; ntk++) {
        float p0 = __builtin_amdgcn_exp2f(sacc[mt][ntk][0]);
        float p1 = __builtin_amdgcn_exp2f(sacc[mt][ntk][1]);
        float p2 = __builtin_amdgcn_exp2f(sacc[mt][ntk][2]);
        float p3 = __builtin_amdgcn_exp2f(sacc[mt][ntk][3]);
        // kk-in-half = ntk*16 + quad*4 + r -> chunk c = ntk*2+(quad>>1), +4 if quad odd
        *(uint2*)&Pmt[l16 * 40 + (ntk * 2 + (quad >> 1)) * 8 + (quad & 1) * 4] =
            make_uint2(pk2(p0, p1), pk2(p2, p3));
      }
      // A-frag: P[q=l16][k = quad*8 + j] (k local to half)
      pf[mt] = *(const half8*)&Pmt[l16 * 40 + quad * 8];
    }

    // O += P V over own kk half (vf reused across mt); l += P 1
    __builtin_amdgcn_s_setprio(1);
    #pragma unroll
    for (int dt = 0; dt < 4; dt++) {
      half8 vf = *(const half8*)&Vsp[(dt * 16 + l16) * 64 + (((koff8 + quad) ^ (l16 & 7)) * 8)];
      #pragma unroll
      for (int mt = 0; mt < 2; mt++)
        oacc[mt][dt] = __builtin_amdgcn_mfma_f32_16x16x32_f16(pf[mt], vf, oacc[mt][dt], 0, 0, 0);
    }
    #pragma unroll
    for (int mt = 0; mt < 2; mt++)
      lacc[mt] = __builtin_amdgcn_mfma_f32_16x16x32_f16(pf[mt], vone, lacc[mt], 0, 0, 0);
    __builtin_amdgcn_s_setprio(0);

    __syncthreads();   // readers done with buf[cur]; prefetch DMA drained
  }

  // ---- pairwise merge: odd wave (kk 32-63) -> LDS; even wave sums + writes.
  // K/V region (32 KB) is dead now; O partial per pair = 32q x 64d f32 = 8 KB.
  float* Oex = (float*)lds + pair * 2048;
  float* Lex = (float*)&lds[16384] + pair * 32;   // in Ps region (after reads)
  if (kh) {
    #pragma unroll
    for (int mt = 0; mt < 2; mt++)
      #pragma unroll
      for (int dt = 0; dt < 4; dt++)
        *(f32x4*)&Oex[(mt * 4 + dt) * 256 + lane * 4] = oacc[mt][dt];
    if (l16 == 0) {
      #pragma unroll
      for (int mt = 0; mt < 2; mt++)
        #pragma unroll
        for (int r = 0; r < 4; r++)
          Lex[mt * 16 + quad * 4 + r] = lacc[mt][r];
    }
  }
  __syncthreads();
  if (!kh) {
    #pragma unroll
    for (int mt = 0; mt < 2; mt++) {
      float linv[4];
      #pragma unroll
      for (int r = 0; r < 4; r++)
        linv[r] = 1.0f / (lacc[mt][r] + Lex[mt * 16 + quad * 4 + r]);
      #pragma unroll
      for (int dt = 0; dt < 4; dt++) {
        f32x4 o2 = *(const f32x4*)&Oex[(mt * 4 + dt) * 256 + lane * 4];
        #pragma unroll
        for (int r = 0; r < 4; r++) {
          int n = qt * 128 + pair * 32 + mt * 16 + quad * 4 + r;
          Ob[((size_t)b * SEQ + n) * CDIM + h * 64 + dt * 16 + l16] =
              f2h((oacc[mt][dt][r] + o2[r]) * linv[r]);
        }
      }
    }
  }
}

// ---------------- launch ----------------
extern "C" void kernel_launch(void* const* d_in, const int* in_sizes, int n_in,
                              void* d_out, int out_size, void* d_ws, size_t ws_size,
                              hipStream_t stream)
{
  const float* x     = (const float*)d_in[0];
  const float* y     = (const float*)d_in[1];
  const float* Wq    = (const float*)d_in[2];
  const float* Wkv   = (const float*)d_in[3];
  const float* taup  = (const float*)d_in[4];
  const float* Wproj = (const float*)d_in[5];
  const float* bproj = (const float*)d_in[6];
  float* out = (float*)d_out;

  char* ws = (char*)d_ws;
  size_t off = 0;
  auto alloc = [&](size_t bytes) { char* p = ws + off; off += bytes; return p; };
  u16* xh  = (u16*)alloc(8192ull * 768 * 2);
  u16* yh  = (u16*)alloc(8192ull * 768 * 2);
  u16* wqh = (u16*)alloc(768ull * 768 * 2);
  u16* wkh = (u16*)alloc(1536ull * 768 * 2);
  u16* wph = (u16*)alloc(768ull * 768 * 2);
  u16* qb  = (u16*)alloc(8192ull * 768 * 2);   // [B,H,N,D] f16, scale folded
  u16* kb  = (u16*)alloc(8192ull * 768 * 2);   // [B,H,N,D]
  u16* vtb = (u16*)alloc(8192ull * 768 * 2);   // [B,H,D,N]
  u16* ao  = (u16*)alloc(8192ull * 768 * 2);   // [B,N,C]

  // one fused convert kernel: x, y, Wq(scaled), Wkv, Wproj
  cvt_all<<<14592, 256, 0, stream>>>(x, y, Wq, Wkv, Wproj, taup,
                                     xh, yh, wqh, wkh, wph);

  // fused QKV GEMM: by<6 -> Q (N=768), by in [6,18) -> KV (N=1536), BN=128
  gemm_k<0, 128, 2><<<dim3(64, 18), 256, 0, stream>>>(xh, yh, wqh, wkh, qb, kb, vtb, nullptr, nullptr);
  attn_kernel<<<dim3(768), 512, 0, stream>>>(qb, kb, vtb, ao);
  gemm_k<2, 64, 3><<<dim3(64, 12), 256, 0, stream>>>(ao, nullptr, wph, nullptr, nullptr, nullptr, nullptr, out, bproj);
}

// Round 11
// 231.081 us; speedup vs baseline: 1.0063x; 1.0030x over previous
//
#include <hip/hip_runtime.h>
#include <math.h>

typedef unsigned short u16;
typedef unsigned int u32;
typedef __fp16 fp16x2 __attribute__((ext_vector_type(2)));
typedef _Float16 half8 __attribute__((ext_vector_type(8)));
typedef float f32x4 __attribute__((ext_vector_type(4)));

#define NH   12
#define SEQ  2048
#define CDIM 768

__device__ __forceinline__ u16 f2h(float f) {
  _Float16 h = (_Float16)f;
  return __builtin_bit_cast(u16, h);
}
__device__ __forceinline__ u32 pk2(float a, float b) {
  fp16x2 h = __builtin_amdgcn_cvt_pkrtz(a, b);    // v_cvt_pk_rtz_f16_f32
  return __builtin_bit_cast(u32, h);
}
// async global->LDS DMA, 16B per lane; LDS dest = wave-uniform base + lane*16
__device__ __forceinline__ void dma16(const u16* g, u16* l) {
  __builtin_amdgcn_global_load_lds(
      (const __attribute__((address_space(1))) u32*)g,
      (__attribute__((address_space(3))) u32*)l, 16, 0, 0);
}

// ---------------- single fused fp32 -> f16 convert (x, y, all weights) -----
// Each block converts 1024 contiguous elements of exactly one tensor.
// Ranges (in blocks): x [0,6144), y [6144,12288), Wq-scaled [12288,12864),
// Wkv [12864,14016), Wproj [14016,14592). Offsets in ELEMENTS throughout.
__global__ __launch_bounds__(256) void cvt_all(
    const float* __restrict__ x, const float* __restrict__ y,
    const float* __restrict__ Wq, const float* __restrict__ Wkv,
    const float* __restrict__ Wp, const float* __restrict__ taup,
    u16* __restrict__ xh, u16* __restrict__ yh,
    u16* __restrict__ wqh, u16* __restrict__ wkh, u16* __restrict__ wph)
{
  const int bx = blockIdx.x;
  const long idx = (long)bx * 1024 + (long)threadIdx.x * 4;  // global elem idx
  const float* in; u16* out; long j; float s = 1.f;
  if (bx < 6144)       { in = x;   out = xh;  j = idx; }
  else if (bx < 12288) { in = y;   out = yh;  j = idx - 6144l * 1024; }
  else if (bx < 12864) {
    float t = *taup;
    float sp = (t > 20.f) ? t : log1pf(expf(t));
    s = (0.125f / (sp + 1e-6f)) * 1.44269504088896340736f;  // qkscale * log2(e)
    in = Wq; out = wqh; j = idx - 12288l * 1024;
  }
  else if (bx < 14016) { in = Wkv; out = wkh; j = idx - 12864l * 1024; }
  else                 { in = Wp;  out = wph; j = idx - 14016l * 1024; }
  float4 f = *(const float4*)(in + j);
  *(uint2*)(out + j) = make_uint2(pk2(f.x * s, f.y * s), pk2(f.z * s, f.w * s));
}

// ---------------- NT GEMM: C[M,N] = A[M,K] @ B[N,K]^T, f16 MFMA, fp32 acc ---
// R4-proven structure: tile 128(M) x BN(N), BK=64, K=768 (12 iters), 4 waves
// as 2x2 quadrants, all-DMA staging (global_load_lds f16), 2-phase prefetch
// (issue t+1 before compute t), one __syncthreads per iter. Chunk-XOR swizzle.
// BN=128 for fused QKV (ratio 2.0 MFMA/ds_read, grid 64x18=1152 blocks);
// BN=96 NEW for proj: N=768=8x96 -> grid (64,8)=512 blocks = exactly 2/CU
// (56 KB LDS), ratio 1.71 (was BN=64: 0.75 ratio).
// MODE 0: FUSED QKV. by<6: A=xh,B=Wq -> q [B,H,N,D] (scale pre-folded);
//         by>=6: A=yh,B=Wkv -> cols[0,768) k; [768,1536) v^T [B,H,D,N]
//         (v^T stored as 8B uint2: 4 consecutive n per lane)
// MODE 2: A=ao,B=Wproj -> fp32 out[M,768] = acc + bias[n]
template<int MODE, int BN, int WPB>
__global__ __launch_bounds__(256, WPB) void gemm_k(
    const u16* __restrict__ A0, const u16* __restrict__ A1,
    const u16* __restrict__ B0, const u16* __restrict__ B1,
    u16* __restrict__ oq, u16* __restrict__ ok, u16* __restrict__ ovt,
    float* __restrict__ outf, const float* __restrict__ bias)
{
  constexpr int NT = BN / 32;                     // n-tiles per wave
  __shared__ __align__(16) u16 As[2][128 * 64];   // [buf][m][k] swizzled, 32 KB
  __shared__ __align__(16) u16 Bs[2][BN * 64];    // [buf][n][k] swizzled
  const int tid = threadIdx.x;
  const int wave = tid >> 6, lane = tid & 63;
  const int quad = lane >> 4, l16 = lane & 15;
  const int wr = wave >> 1, wc = wave & 1;        // wave quadrant (64m x BN/2)
  const int row0 = blockIdx.x * 128;
  const int by = blockIdx.y;

  const u16* A; const u16* Bm; int cb;
  if (MODE == 0) {
    if (by < 6) { A = A0; Bm = B0; cb = by; }
    else        { A = A1; Bm = B1; cb = by - 6; }
  } else {
    A = A0; Bm = B0; cb = by;
  }
  const int col0 = cb * BN;

  const int sub = lane >> 3;                   // row within an 8-row DMA slab
  const int csw = ((lane & 7) ^ sub) * 8;      // swizzled source chunk (elems)

  f32x4 acc[4][NT] = {};

  auto stage = [&](int k0, int bsel) {
    #pragma unroll
    for (int i = 0; i < 4; i++) {
      int ii = wave * 4 + i;                   // A slabs 0..15 (8 rows each)
      dma16(A + (size_t)(row0 + ii * 8 + sub) * 768 + k0 + csw, &As[bsel][ii * 512]);
    }
    #pragma unroll
    for (int i = 0; i < BN / 32; i++) {
      int ii = wave * (BN / 32) + i;           // B slabs 0..BN/8-1
      dma16(Bm + (size_t)(col0 + ii * 8 + sub) * 768 + k0 + csw, &Bs[bsel][ii * 512]);
    }
  };

  stage(0, 0);
  __syncthreads();                             // drain tile-0 DMA

  #pragma unroll 1
  for (int t = 0; t < 12; t++) {
    const int cur = t & 1;
    if (t + 1 < 12) stage((t + 1) << 6, cur ^ 1);   // prefetch next tile
    const u16* Asp = As[cur];
    const u16* Bsp = Bs[cur];
    #pragma unroll
    for (int ks = 0; ks < 2; ks++) {
      half8 af[4], bfr[NT];
      #pragma unroll
      for (int mt = 0; mt < 4; mt++)
        af[mt] = *(const half8*)&Asp[(wr * 64 + mt * 16 + l16) * 64 + (((ks * 4 + quad) ^ (l16 & 7)) * 8)];
      #pragma unroll
      for (int nt = 0; nt < NT; nt++)
        bfr[nt] = *(const half8*)&Bsp[(wc * (BN / 2) + nt * 16 + l16) * 64 + (((ks * 4 + quad) ^ (l16 & 7)) * 8)];
      #pragma unroll
      for (int mt = 0; mt < 4; mt++)
        #pragma unroll
        for (int nt = 0; nt < NT; nt++)
          acc[mt][nt] = __builtin_amdgcn_mfma_f32_16x16x32_f16(af[mt], bfr[nt], acc[mt][nt], 0, 0, 0);
    }
    __syncthreads();   // readers done with buf[cur]; prefetch DMA drained
  }

  // epilogue: C layout col=lane&15, row=quad*4+reg
  #pragma unroll
  for (int mt = 0; mt < 4; mt++)
  #pragma unroll
  for (int nt = 0; nt < NT; nt++) {
    int gm0 = row0 + wr * 64 + mt * 16 + quad * 4;
    int gn = col0 + wc * (BN / 2) + nt * 16 + l16;
    f32x4 v = acc[mt][nt];
    if (MODE == 0) {
      int b = gm0 >> 11, n0 = gm0 & 2047;
      if (by < 6) {
        int h = gn >> 6, d = gn & 63;
        size_t base = (((size_t)(b * NH + h)) * SEQ + n0) * 64 + d;
        #pragma unroll
        for (int r = 0; r < 4; r++) oq[base + (size_t)r * 64] = f2h(v[r]);
      } else if (gn < CDIM) {
        int h = gn >> 6, d = gn & 63;
        size_t base = (((size_t)(b * NH + h)) * SEQ + n0) * 64 + d;
        #pragma unroll
        for (int r = 0; r < 4; r++) ok[base + (size_t)r * 64] = f2h(v[r]);
      } else {
        int c = gn - CDIM;
        int h = c >> 6, d = c & 63;
        *(uint2*)&ovt[(((size_t)(b * NH + h)) * 64 + d) * SEQ + n0] =
            make_uint2(pk2(v[0], v[1]), pk2(v[2], v[3]));   // V^T: 4 consecutive n
      }
    } else {
      float bv = bias[gn];
      #pragma unroll
      for (int r = 0; r < 4; r++)
        outf[(size_t)(gm0 + r) * CDIM + gn] = v[r] + bv;
    }
  }
}

// ---------------- flash attention (transposed-S, f16, no-max softmax) ------
// R8 kernel with ONE change: ALL s_setprio removed (A/B test). Rationale:
// five structural variants (occupancy 25->52%, intensity 1.0->1.8 MFMA/read,
// barrier placement, software pipeline, kk-split) all pinned at 67.6-70 us /
// MfmaUtil 34-36% -- resident waves behave serialized. setprio has wrapped
// every MFMA cluster (incl. its ds_reads + lgkm waits) since R2, never
// isolated; T5 measured -14 TF on exactly this barrier-locked multi-wave
// shape (m190). Prio-1 clusters win arbitration over other waves' clusters
// -> cluster-serial execution = the observed 3x chain period.
// QBLK=128, grid 768, chunked XCD swizzle (96 blocks = 6 heads/XCD).
// 4 waves x 32 q-rows. KV tile 64, 2-phase double-buffered DMA staging.
// St = K Q^T; fixed-shift softmax p=exp2(s); swizzled Ps relayout;
// row-sum l on the matrix pipe (lacc rows == oacc rows).
__global__ __launch_bounds__(256, 3) void attn_kernel(
    const u16* __restrict__ Q, const u16* __restrict__ Kb,
    const u16* __restrict__ Vtg, u16* __restrict__ Ob)
{
  __shared__ __align__(16) u16 Ks[2][64 * 64];    // [buf][kk][d] swizzled, 2x8 KB
  __shared__ __align__(16) u16 Vs[2][64 * 64];    // [buf][d][kk] swizzled, 2x8 KB
  __shared__ __align__(16) u16 Ps[4 * 16 * 64];   // per-wave 16x64 swizzled, 8 KB

  // bijective chunked XCD swizzle: 768 blocks = 8 XCDs x 96
  const int bid = (blockIdx.x & 7) * 96 + (blockIdx.x >> 3);
  const int qt = bid & 15;
  const int bh = bid >> 4;
  const int b = bh / NH, h = bh % NH;
  const u16* Qp = Q   + (size_t)bh * SEQ * 64;
  const u16* Kp = Kb  + (size_t)bh * SEQ * 64;
  const u16* Vp = Vtg + (size_t)bh * 64 * SEQ;

  const int tid = threadIdx.x;
  const int wave = tid >> 6, lane = tid & 63;
  const int quad = lane >> 4, l16 = lane & 15;
  const int sub = lane >> 3;
  const int csw = ((lane & 7) ^ sub) * 8;
  u16* Pw = Ps + wave * 16 * 64;

  half8 vone;
  #pragma unroll
  for (int j = 0; j < 8; j++) vone[j] = (_Float16)1.0f;

  // Q fragments (B-operand): Q[m=l16][d=ks*32+quad*8+j], scale pre-folded
  half8 qf[2][2];
  #pragma unroll
  for (int mt = 0; mt < 2; mt++)
    #pragma unroll
    for (int ks = 0; ks < 2; ks++)
      qf[mt][ks] = *(const half8*)(Qp + (size_t)(qt * 128 + wave * 32 + mt * 16 + l16) * 64 + ks * 32 + quad * 8);

  f32x4 oacc[2][4] = {};
  f32x4 lacc[2] = {};                          // row-sums via MFMA w/ ones

  auto stage = [&](int kt, int bsel) {
    #pragma unroll
    for (int i = 0; i < 2; i++) {
      int ii = wave * 2 + i;                   // slabs 0..7 (8 rows each)
      dma16(Kp + (size_t)(kt * 64 + ii * 8 + sub) * 64 + csw, &Ks[bsel][ii * 512]);
      dma16(Vp + (size_t)(ii * 8 + sub) * SEQ + kt * 64 + csw, &Vs[bsel][ii * 512]);
    }
  };

  stage(0, 0);
  __syncthreads();                             // drain tile-0 DMA

  #pragma unroll 1
  for (int kt = 0; kt < SEQ / 64; kt++) {
    const int cur = kt & 1;
    if (kt + 1 < SEQ / 64) stage(kt + 1, cur ^ 1);   // prefetch next K/V tile
    const u16* Ksp = Ks[cur];
    const u16* Vsp = Vs[cur];

    // St = K Q^T : sacc[mt][ntk] holds St[kk=ntk*16+quad*4+r][m=l16]
    f32x4 sacc[2][4] = {};
    #pragma unroll
    for (int ks = 0; ks < 2; ks++) {
      #pragma unroll
      for (int ntk = 0; ntk < 4; ntk++) {
        half8 kf = *(const half8*)&Ksp[(ntk * 16 + l16) * 64 + (((ks * 4 + quad) ^ (l16 & 7)) * 8)];
        #pragma unroll
        for (int mt = 0; mt < 2; mt++)
          sacc[mt][ntk] = __builtin_amdgcn_mfma_f32_16x16x32_f16(kf, qf[mt][ks], sacc[mt][ntk], 0, 0, 0);
      }
    }

    // softmax (fixed shift): p = exp2(s); P -> swizzled Ps (C->A layout), per mt
    half8 pf[2][2];
    #pragma unroll
    for (int mt = 0; mt < 2; mt++) {
      #pragma unroll
      for (int ntk = 0; ntk < 4; ntk++) {
        float p0 = __builtin_amdgcn_exp2f(sacc[mt][ntk][0]);
        float p1 = __builtin_amdgcn_exp2f(sacc[mt][ntk][1]);
        float p2 = __builtin_amdgcn_exp2f(sacc[mt][ntk][2]);
        float p3 = __builtin_amdgcn_exp2f(sacc[mt][ntk][3]);
        *(uint2*)&Pw[l16 * 64 + (((ntk * 2 + (quad >> 1)) ^ (l16 & 7)) * 8) + (quad & 1) * 4] =
            make_uint2(pk2(p0, p1), pk2(p2, p3));
      }
      pf[mt][0] = *(const half8*)&Pw[l16 * 64 + ((quad ^ (l16 & 7)) * 8)];
      pf[mt][1] = *(const half8*)&Pw[l16 * 64 + (((4 + quad) ^ (l16 & 7)) * 8)];
    }

    // O += P V (vf reused across mt); l += P 1 on the matrix pipe
    #pragma unroll
    for (int ks = 0; ks < 2; ks++) {
      #pragma unroll
      for (int dt = 0; dt < 4; dt++) {
        half8 vf = *(const half8*)&Vsp[(dt * 16 + l16) * 64 + (((ks * 4 + quad) ^ (l16 & 7)) * 8)];
        #pragma unroll
        for (int mt = 0; mt < 2; mt++)
          oacc[mt][dt] = __builtin_amdgcn_mfma_f32_16x16x32_f16(pf[mt][ks], vf, oacc[mt][dt], 0, 0, 0);
      }
      #pragma unroll
      for (int mt = 0; mt < 2; mt++)
        lacc[mt] = __builtin_amdgcn_mfma_f32_16x16x32_f16(pf[mt][ks], vone, lacc[mt], 0, 0, 0);
    }

    __syncthreads();   // readers done with buf[cur]; prefetch DMA drained
  }

  // epilogue: O / l -> ao[b][n][h*64+d] (f16); lacc row layout == oacc rows
  #pragma unroll
  for (int mt = 0; mt < 2; mt++) {
    #pragma unroll
    for (int r = 0; r < 4; r++) {
      float inv = 1.0f / lacc[mt][r];
      int n = qt * 128 + wave * 32 + mt * 16 + quad * 4 + r;
      size_t base = ((size_t)b * SEQ + n) * CDIM + h * 64;
      #pragma unroll
      for (int dt = 0; dt < 4; dt++)
        Ob[base + dt * 16 + l16] = f2h(oacc[mt][dt][r] * inv);
    }
  }
}

// ---------------- launch ----------------
extern "C" void kernel_launch(void* const* d_in, const int* in_sizes, int n_in,
                              void* d_out, int out_size, void* d_ws, size_t ws_size,
                              hipStream_t stream)
{
  const float* x     = (const float*)d_in[0];
  const float* y     = (const float*)d_in[1];
  const float* Wq    = (const float*)d_in[2];
  const float* Wkv   = (const float*)d_in[3];
  const float* taup  = (const float*)d_in[4];
  const float* Wproj = (const float*)d_in[5];
  const float* bproj = (const float*)d_in[6];
  float* out = (float*)d_out;

  char* ws = (char*)d_ws;
  size_t off = 0;
  auto alloc = [&](size_t bytes) { char* p = ws + off; off += bytes; return p; };
  u16* xh  = (u16*)alloc(8192ull * 768 * 2);
  u16* yh  = (u16*)alloc(8192ull * 768 * 2);
  u16* wqh = (u16*)alloc(768ull * 768 * 2);
  u16* wkh = (u16*)alloc(1536ull * 768 * 2);
  u16* wph = (u16*)alloc(768ull * 768 * 2);
  u16* qb  = (u16*)alloc(8192ull * 768 * 2);   // [B,H,N,D] f16, scale folded
  u16* kb  = (u16*)alloc(8192ull * 768 * 2);   // [B,H,N,D]
  u16* vtb = (u16*)alloc(8192ull * 768 * 2);   // [B,H,D,N]
  u16* ao  = (u16*)alloc(8192ull * 768 * 2);   // [B,N,C]

  // one fused convert kernel: x, y, Wq(scaled), Wkv, Wproj
  cvt_all<<<14592, 256, 0, stream>>>(x, y, Wq, Wkv, Wproj, taup,
                                     xh, yh, wqh, wkh, wph);

  // fused QKV GEMM: by<6 -> Q (N=768), by in [6,18) -> KV (N=1536), BN=128
  gemm_k<0, 128, 2><<<dim3(64, 18), 256, 0, stream>>>(xh, yh, wqh, wkh, qb, kb, vtb, nullptr, nullptr);
  attn_kernel<<<dim3(768), 256, 0, stream>>>(qb, kb, vtb, ao);
  // proj GEMM: BN=96 -> grid (64,8) = 512 blocks = exactly 2/CU
  gemm_k<2, 96, 2><<<dim3(64, 8), 256, 0, stream>>>(ao, nullptr, wph, nullptr, nullptr, nullptr, nullptr, out, bproj);
}